// Round 1
// 780.357 us; speedup vs baseline: 1.0891x; 1.0891x over previous
//
#include <hip/hip_runtime.h>

typedef unsigned short u16;
typedef __attribute__((ext_vector_type(8))) short short8;
typedef __attribute__((ext_vector_type(4))) float f32x4;
typedef __attribute__((ext_vector_type(4))) int i32x4;

// ---------- bf16 helpers (RNE) ----------
__device__ __forceinline__ float bf2f(u16 u) {
  union { unsigned u; float f; } v; v.u = ((unsigned)u) << 16; return v.f;
}
__device__ __forceinline__ u16 f2bf(float f) {
  union { float f; unsigned u; } v; v.f = f;
  unsigned r = (v.u + 0x7FFFu + ((v.u >> 16) & 1u)) >> 16;
  return (u16)r;
}
__device__ __forceinline__ float flushv(float t, float sentinel) {
  if (t != t || fabsf(t) > 3.0e38f) return sentinel;
  return t;
}
// load 8 fp32 and convert to bf16x8
__device__ __forceinline__ short8 ld8f(const float* p) {
  const float4 f0 = *(const float4*)p;
  const float4 f1 = *(const float4*)(p + 4);
  short8 r;
  r[0] = (short)f2bf(f0.x); r[1] = (short)f2bf(f0.y);
  r[2] = (short)f2bf(f0.z); r[3] = (short)f2bf(f0.w);
  r[4] = (short)f2bf(f1.x); r[5] = (short)f2bf(f1.y);
  r[6] = (short)f2bf(f1.z); r[7] = (short)f2bf(f1.w);
  return r;
}

// ================= GEMM: C[M,N] = A[M,K] @ W[N,K]^T =================
// AF/WF: operand is fp32 in global (convert to bf16 at staging). OF: output fp32.
// m93 structure: 128x128 tile, BK=32, VGPR staging, 2 barriers, 16x16x32 MFMA.
template <bool AF, bool WF, bool OF>
__global__ __launch_bounds__(256) void gemm_bt(
    const void* __restrict__ Ap,
    const void* __restrict__ Wp0, const void* __restrict__ Wp1, const void* __restrict__ Wp2,
    void* __restrict__ O0, void* __restrict__ O1, void* __restrict__ O2,
    int M, int N, int K, float sentinel)
{
  __shared__ __align__(16) u16 As[128 * 32];
  __shared__ __align__(16) u16 Bs[128 * 32];

  const void* Wp; void* O;
  if (blockIdx.z == 0)      { Wp = Wp0; O = O0; }
  else if (blockIdx.z == 1) { Wp = Wp1; O = O1; }
  else                      { Wp = Wp2; O = O2; }

  const float* Af = (const float*)Ap;  const u16* Ab = (const u16*)Ap;
  const float* Wf = (const float*)Wp;  const u16* Wb = (const u16*)Wp;

  const int tid  = threadIdx.x;
  const int wave = tid >> 6;
  const int lane = tid & 63;
  const int quad = lane >> 4;
  const int l15  = lane & 15;

  const int m0 = blockIdx.y * 128;
  const int n0 = blockIdx.x * 128;
  const int wm = (wave >> 1) * 64;
  const int wn = (wave & 1) * 64;

  const int e0 = wave * 1024 + lane * 8;
  const int e1 = e0 + 512;
  const int r0 = e0 >> 5, c0 = e0 & 31;
  const int r1 = e1 >> 5, c1 = e1 & 31;

  const long aoff0 = (long)(m0 + r0) * K + c0;
  const long aoff1 = (long)(m0 + r1) * K + c1;
  const long boff0 = (long)(n0 + r0) * K + c0;
  const long boff1 = (long)(n0 + r1) * K + c1;

  const f32x4 zero = {0.f, 0.f, 0.f, 0.f};
  f32x4 acc[4][4];
#pragma unroll
  for (int i = 0; i < 4; ++i)
#pragma unroll
    for (int j = 0; j < 4; ++j) acc[i][j] = zero;

  for (int k0 = 0; k0 < K; k0 += 32) {
    short8 a0, a1, b0, b1;
    if constexpr (AF) {
      a0 = ld8f(Af + aoff0 + k0);
      a1 = ld8f(Af + aoff1 + k0);
    } else {
      a0 = *(const short8*)(Ab + aoff0 + k0);
      a1 = *(const short8*)(Ab + aoff1 + k0);
    }
    if constexpr (WF) {
      b0 = ld8f(Wf + boff0 + k0);
      b1 = ld8f(Wf + boff1 + k0);
    } else {
      b0 = *(const short8*)(Wb + boff0 + k0);
      b1 = *(const short8*)(Wb + boff1 + k0);
    }

    __syncthreads();
    *(short8*)&As[e0] = a0;
    *(short8*)&As[e1] = a1;
    *(short8*)&Bs[e0] = b0;
    *(short8*)&Bs[e1] = b1;
    __syncthreads();

    short8 af[4], bf[4];
#pragma unroll
    for (int i = 0; i < 4; ++i)
      af[i] = *(const short8*)&As[(wm + i * 16 + l15) * 32 + quad * 8];
#pragma unroll
    for (int j = 0; j < 4; ++j)
      bf[j] = *(const short8*)&Bs[(wn + j * 16 + l15) * 32 + quad * 8];
#pragma unroll
    for (int i = 0; i < 4; ++i)
#pragma unroll
      for (int j = 0; j < 4; ++j)
        acc[i][j] = __builtin_amdgcn_mfma_f32_16x16x32_bf16(af[i], bf[j], acc[i][j], 0, 0, 0);
  }

  // C/D layout: col = lane&15, row = quad*4 + reg (verified m89/m91)
#pragma unroll
  for (int i = 0; i < 4; ++i) {
    const int row0 = m0 + wm + i * 16 + quad * 4;
#pragma unroll
    for (int j = 0; j < 4; ++j) {
      const int col = n0 + wn + j * 16 + l15;
#pragma unroll
      for (int r = 0; r < 4; ++r) {
        const float val = flushv(acc[i][j][r], sentinel);
        if constexpr (OF)
          ((float*)O)[(long)(row0 + r) * N + col] = val;
        else
          ((u16*)O)[(long)(row0 + r) * N + col] = f2bf(val);
      }
    }
  }
}

// ================= RoPE (chunk-half), in-place on bf16 Q and K =================
__global__ __launch_bounds__(256) void rope_kernel(u16* __restrict__ Q, u16* __restrict__ K)
{
  int t = blockIdx.x * 256 + threadIdx.x;
  const int half = 2 * 2048 * 16 * 64;
  u16* P = Q;
  if (t >= half) { P = K; t -= half; }
  const int i = t & 63;
  const int s = (t >> 10) & 2047;
  const long off = ((long)(t >> 6) << 7) + i;

  const float inv_freq = expf((float)i * -0.14391156831212787f);  // 10000^(-i/64)
  const float fr = (float)s * inv_freq;
  float sn, cs;
  sincosf(fr, &sn, &cs);

  const float q1 = bf2f(P[off]);
  const float q2 = bf2f(P[off + 64]);
  P[off]      = f2bf(q1 * cs - q2 * sn);
  P[off + 64] = f2bf(q1 * sn + q2 * cs);
}

// ================= causal flash attention (barrier-free, per-wave) =================
// Q,K: [b,s,h*128+d] bf16.  VT: [h*128+d][b*2048+s] bf16 (pre-transposed by gemm).
// K and V^T fragments are read DIRECTLY from global (L1/L2-resident; no LDS staging,
// no LDS transpose, no __syncthreads).  Per-wave S^T exchange in padded LDS (2-way
// banks = free); P fragment distributed via 4 shuffles; m/l/alpha in registers.
// AO may alias Q: each (b,h,row-group) is read and written only by its own wave.
__global__ __launch_bounds__(256) void attn_kernel(
    const u16* __restrict__ Q, const u16* __restrict__ K,
    const u16* __restrict__ VT, u16* __restrict__ AO)
{
  __shared__ float St[4][32 * 17];   // per-wave S^T[key][q], stride 17 (2-way banks)

  const int tid  = threadIdx.x;
  const int wave = tid >> 6;
  const int lane = tid & 63;
  const int quad = lane >> 4;
  const int l15  = lane & 15;
  const int row4 = lane >> 2;   // softmax: q-row owned by this lane group
  const int sub  = lane & 3;    // 4 lanes per row, 8 cols each

  // XCD-aware remap: all 32 q-blocks of one (b,h) land on one XCD (K/V L2 locality).
  const int lin = blockIdx.x + (blockIdx.y << 5);   // 0..1023
  const int xcd = lin & 7;
  const int idx = lin >> 3;                          // 0..127
  const int qb  = idx & 31;
  const int bh  = (xcd << 2) | (idx >> 5);           // bijective: 8*4 = 32 bh values
  const int b   = bh >> 4;
  const int h   = bh & 15;

  const long base = (long)b * 2048 * 2048 + (long)h * 128;
  const long vtb  = (long)h * 128 * 4096 + (long)b * 2048;
  const int q0w = qb * 64 + wave * 16;

  short8 qa[4];
#pragma unroll
  for (int c = 0; c < 4; ++c)
    qa[c] = *(const short8*)&Q[base + (long)(q0w + l15) * 2048 + c * 32 + quad * 8];

  const f32x4 zero = {0.f, 0.f, 0.f, 0.f};
  f32x4 o[8];
#pragma unroll
  for (int c = 0; c < 8; ++c) o[c] = zero;

  float mreg = -1e30f, lreg = 0.f;   // running max / denom for row row4
  float* S = St[wave];
  const float scale = 0.08838834764831845f;  // 1/sqrt(128)
  const int qi = q0w + row4;
  const int psrc = (l15 << 2) | quad;        // src lane for P fragment shuffle

  // waves 0-1 (rows q0w..q0w+31 of the 64-row block) skip the fully-masked last tile
  const int njb = qb * 2 + 1 + (wave >> 1);
  for (int jb = 0; jb < njb; ++jb) {
    const int j0 = jb * 32;

    // ---- QK^T: K fragments straight from global (L1-shared across the 4 waves) ----
    f32x4 s0 = zero, s1 = zero;
#pragma unroll
    for (int c = 0; c < 4; ++c) {
      short8 kb0 = *(const short8*)&K[base + (long)(j0 + l15) * 2048 + c * 32 + quad * 8];
      short8 kb1 = *(const short8*)&K[base + (long)(j0 + 16 + l15) * 2048 + c * 32 + quad * 8];
      s0 = __builtin_amdgcn_mfma_f32_16x16x32_bf16(qa[c], kb0, s0, 0, 0, 0);
      s1 = __builtin_amdgcn_mfma_f32_16x16x32_bf16(qa[c], kb1, s1, 0, 0, 0);
    }

    // ---- layout swap via per-wave S^T LDS (write 2-way, read 2-way: free) ----
#pragma unroll
    for (int r = 0; r < 4; ++r) {
      S[l15 * 17 + quad * 4 + r]        = s0[r];
      S[(l15 + 16) * 17 + quad * 4 + r] = s1[r];
    }
    __builtin_amdgcn_wave_barrier();

    // ---- online softmax: row row4, 4 lanes x 8 cols ----
    float sv[8];
    float pmax = -1e30f;
#pragma unroll
    for (int j = 0; j < 8; ++j) {
      const int col = sub * 8 + j;
      float s = S[col * 17 + row4] * scale;
      if (j0 + col > qi) s = -1e30f;
      sv[j] = s;
      pmax = fmaxf(pmax, s);
    }
    __builtin_amdgcn_wave_barrier();
    pmax = fmaxf(pmax, __shfl_xor(pmax, 1, 64));
    pmax = fmaxf(pmax, __shfl_xor(pmax, 2, 64));
    const float mprev = mreg;
    const float mnew  = fmaxf(mprev, pmax);
    float alpha, psum = 0.f;
    if (mnew <= -5e29f) {
      alpha = 1.f;
#pragma unroll
      for (int j = 0; j < 8; ++j) sv[j] = 0.f;
    } else {
      alpha = __expf(mprev - mnew);
#pragma unroll
      for (int j = 0; j < 8; ++j) {
        sv[j] = __expf(sv[j] - mnew);
        psum += sv[j];
      }
    }
    psum += __shfl_xor(psum, 1, 64);
    psum += __shfl_xor(psum, 2, 64);
    lreg = lreg * alpha + psum;
    mreg = mnew;

    // ---- P -> A-fragment layout via 4 shuffles (no LDS round-trip) ----
    short8 pr;
#pragma unroll
    for (int j = 0; j < 8; ++j) pr[j] = (short)f2bf(sv[j]);
    i32x4 pi = *(i32x4*)&pr;
    i32x4 pt;
    pt[0] = __shfl(pi[0], psrc, 64);
    pt[1] = __shfl(pi[1], psrc, 64);
    pt[2] = __shfl(pi[2], psrc, 64);
    pt[3] = __shfl(pi[3], psrc, 64);
    const short8 pa = *(const short8*)&pt;

    // ---- rescale O by alpha of rows quad*4+r (broadcast via shuffle) ----
    float av[4];
#pragma unroll
    for (int r = 0; r < 4; ++r) av[r] = __shfl(alpha, (quad * 4 + r) << 2, 64);
#pragma unroll
    for (int c = 0; c < 8; ++c) {
      o[c][0] *= av[0]; o[c][1] *= av[1]; o[c][2] *= av[2]; o[c][3] *= av[3];
    }

    // ---- PV: V^T fragments straight from global (no LDS transpose) ----
#pragma unroll
    for (int c = 0; c < 8; ++c) {
      short8 vb = *(const short8*)&VT[vtb + (long)(c * 16 + l15) * 4096 + j0 + quad * 8];
      o[c] = __builtin_amdgcn_mfma_f32_16x16x32_bf16(pa, vb, o[c], 0, 0, 0);
    }
  }

  // ---- epilogue: normalize and store ----
#pragma unroll
  for (int r = 0; r < 4; ++r) {
    const float lr  = __shfl(lreg, (quad * 4 + r) << 2, 64);
    const float inv = 1.0f / lr;
    const long rowoff = base + (long)(q0w + quad * 4 + r) * 2048;
#pragma unroll
    for (int c = 0; c < 8; ++c)
      AO[rowoff + c * 16 + l15] = f2bf(flushv(o[c][r] * inv, 9999.f));
  }
}

// ================= diagnostic fill =================
__global__ __launch_bounds__(256) void fill_kernel(float* __restrict__ out, long n, float v)
{
  const long t = (long)blockIdx.x * 256 + threadIdx.x;
  if (t < n) out[t] = v;
}

// ================= launch =================
extern "C" void kernel_launch(void* const* d_in, const int* in_sizes, int n_in,
                              void* d_out, int out_size, void* d_ws, size_t ws_size,
                              hipStream_t stream)
{
  // Inputs fp32 (x, Wq, Wk, Wv, Wo); OUTPUT fp32 (reference dtype).
  const float* x  = (const float*)d_in[0];
  const float* Wq = (const float*)d_in[1];
  const float* Wk = (const float*)d_in[2];
  const float* Wv = (const float*)d_in[3];
  const float* Wo = (const float*)d_in[4];
  float* out = (float*)d_out;

  const long QSZ = (long)2 * 2048 * 2048;  // 8388608 elems

  // ws guard (needs 48 MB of bf16 scratch); sentinel 1111 localizes
  if (ws_size < (size_t)3 * QSZ * sizeof(u16)) {
    fill_kernel<<<(int)((QSZ + 255) / 256), 256, 0, stream>>>(out, QSZ, 1111.f);
    return;
  }

  u16* ws = (u16*)d_ws;
  u16* q  = ws;            // bf16 internal
  u16* k  = ws + QSZ;
  u16* v  = ws + 2 * QSZ;  // V^T: [2048 d][4096 tok]
  u16* ao = q;             // attention output in-place over q (partition-safe)

  // sentinels: QKV=7777, attention=9999, outproj=5555, ws=1111
  // Q,K projections: [4096 tok][2048 d]
  gemm_bt<true, true, false><<<dim3(16, 32, 2), 256, 0, stream>>>(
      x, Wq, Wk, Wk, q, k, k, 4096, 2048, 2048, 7777.f);
  // V^T = Wv @ x^T : C[d][tok] = sum_k Wv[d][k] x[tok][k]  -> [2048][4096]
  gemm_bt<true, true, false><<<dim3(32, 16, 1), 256, 0, stream>>>(
      Wv, x, x, x, v, v, v, 2048, 4096, 2048, 7777.f);
  rope_kernel<<<32768, 256, 0, stream>>>(q, k);
  attn_kernel<<<dim3(32, 32), 256, 0, stream>>>(q, k, v, ao);
  gemm_bt<false, true, true><<<dim3(16, 32, 1), 256, 0, stream>>>(
      ao, Wo, Wo, Wo, out, out, out, 4096, 2048, 2048, 5555.f);
}

// Round 2
// 701.629 us; speedup vs baseline: 1.2113x; 1.1122x over previous
//
#include <hip/hip_runtime.h>

typedef unsigned short u16;
typedef __attribute__((ext_vector_type(8))) short short8;
typedef __attribute__((ext_vector_type(4))) float f32x4;
typedef __attribute__((ext_vector_type(4))) int i32x4;

// ---------- bf16 helpers (RNE) ----------
__device__ __forceinline__ float bf2f(u16 u) {
  union { unsigned u; float f; } v; v.u = ((unsigned)u) << 16; return v.f;
}
__device__ __forceinline__ u16 f2bf(float f) {
  union { float f; unsigned u; } v; v.f = f;
  unsigned r = (v.u + 0x7FFFu + ((v.u >> 16) & 1u)) >> 16;
  return (u16)r;
}
__device__ __forceinline__ float flushv(float t, float sentinel) {
  if (t != t || fabsf(t) > 3.0e38f) return sentinel;
  return t;
}
// load 8 fp32 and convert to bf16x8
__device__ __forceinline__ short8 ld8f(const float* p) {
  const float4 f0 = *(const float4*)p;
  const float4 f1 = *(const float4*)(p + 4);
  short8 r;
  r[0] = (short)f2bf(f0.x); r[1] = (short)f2bf(f0.y);
  r[2] = (short)f2bf(f0.z); r[3] = (short)f2bf(f0.w);
  r[4] = (short)f2bf(f1.x); r[5] = (short)f2bf(f1.y);
  r[6] = (short)f2bf(f1.z); r[7] = (short)f2bf(f1.w);
  return r;
}

// ================= GEMM: C[M,N] = A[M,K] @ W[N,K]^T =================
// AF/WF: operand is fp32 in global (convert to bf16 at staging). OF: output fp32.
// m93 structure: 128x128 tile, BK=32, VGPR staging, 2 barriers, 16x16x32 MFMA.
template <bool AF, bool WF, bool OF>
__global__ __launch_bounds__(256) void gemm_bt(
    const void* __restrict__ Ap,
    const void* __restrict__ Wp0, const void* __restrict__ Wp1, const void* __restrict__ Wp2,
    void* __restrict__ O0, void* __restrict__ O1, void* __restrict__ O2,
    int M, int N, int K, float sentinel)
{
  __shared__ __align__(16) u16 As[128 * 32];
  __shared__ __align__(16) u16 Bs[128 * 32];

  const void* Wp; void* O;
  if (blockIdx.z == 0)      { Wp = Wp0; O = O0; }
  else if (blockIdx.z == 1) { Wp = Wp1; O = O1; }
  else                      { Wp = Wp2; O = O2; }

  const float* Af = (const float*)Ap;  const u16* Ab = (const u16*)Ap;
  const float* Wf = (const float*)Wp;  const u16* Wb = (const u16*)Wp;

  const int tid  = threadIdx.x;
  const int wave = tid >> 6;
  const int lane = tid & 63;
  const int quad = lane >> 4;
  const int l15  = lane & 15;

  const int m0 = blockIdx.y * 128;
  const int n0 = blockIdx.x * 128;
  const int wm = (wave >> 1) * 64;
  const int wn = (wave & 1) * 64;

  const int e0 = wave * 1024 + lane * 8;
  const int e1 = e0 + 512;
  const int r0 = e0 >> 5, c0 = e0 & 31;
  const int r1 = e1 >> 5, c1 = e1 & 31;

  const long aoff0 = (long)(m0 + r0) * K + c0;
  const long aoff1 = (long)(m0 + r1) * K + c1;
  const long boff0 = (long)(n0 + r0) * K + c0;
  const long boff1 = (long)(n0 + r1) * K + c1;

  const f32x4 zero = {0.f, 0.f, 0.f, 0.f};
  f32x4 acc[4][4];
#pragma unroll
  for (int i = 0; i < 4; ++i)
#pragma unroll
    for (int j = 0; j < 4; ++j) acc[i][j] = zero;

  for (int k0 = 0; k0 < K; k0 += 32) {
    short8 a0, a1, b0, b1;
    if constexpr (AF) {
      a0 = ld8f(Af + aoff0 + k0);
      a1 = ld8f(Af + aoff1 + k0);
    } else {
      a0 = *(const short8*)(Ab + aoff0 + k0);
      a1 = *(const short8*)(Ab + aoff1 + k0);
    }
    if constexpr (WF) {
      b0 = ld8f(Wf + boff0 + k0);
      b1 = ld8f(Wf + boff1 + k0);
    } else {
      b0 = *(const short8*)(Wb + boff0 + k0);
      b1 = *(const short8*)(Wb + boff1 + k0);
    }

    __syncthreads();
    *(short8*)&As[e0] = a0;
    *(short8*)&As[e1] = a1;
    *(short8*)&Bs[e0] = b0;
    *(short8*)&Bs[e1] = b1;
    __syncthreads();

    short8 af[4], bf[4];
#pragma unroll
    for (int i = 0; i < 4; ++i)
      af[i] = *(const short8*)&As[(wm + i * 16 + l15) * 32 + quad * 8];
#pragma unroll
    for (int j = 0; j < 4; ++j)
      bf[j] = *(const short8*)&Bs[(wn + j * 16 + l15) * 32 + quad * 8];
#pragma unroll
    for (int i = 0; i < 4; ++i)
#pragma unroll
      for (int j = 0; j < 4; ++j)
        acc[i][j] = __builtin_amdgcn_mfma_f32_16x16x32_bf16(af[i], bf[j], acc[i][j], 0, 0, 0);
  }

  // C/D layout: col = lane&15, row = quad*4 + reg (verified m89/m91)
#pragma unroll
  for (int i = 0; i < 4; ++i) {
    const int row0 = m0 + wm + i * 16 + quad * 4;
#pragma unroll
    for (int j = 0; j < 4; ++j) {
      const int col = n0 + wn + j * 16 + l15;
#pragma unroll
      for (int r = 0; r < 4; ++r) {
        const float val = flushv(acc[i][j][r], sentinel);
        if constexpr (OF)
          ((float*)O)[(long)(row0 + r) * N + col] = val;
        else
          ((u16*)O)[(long)(row0 + r) * N + col] = f2bf(val);
      }
    }
  }
}

// ================= RoPE (chunk-half), in-place on bf16 Q and K =================
__global__ __launch_bounds__(256) void rope_kernel(u16* __restrict__ Q, u16* __restrict__ K)
{
  int t = blockIdx.x * 256 + threadIdx.x;
  const int half = 2 * 2048 * 16 * 64;
  u16* P = Q;
  if (t >= half) { P = K; t -= half; }
  const int i = t & 63;
  const int s = (t >> 10) & 2047;
  const long off = ((long)(t >> 6) << 7) + i;

  const float inv_freq = expf((float)i * -0.14391156831212787f);  // 10000^(-i/64)
  const float fr = (float)s * inv_freq;
  float sn, cs;
  sincosf(fr, &sn, &cs);

  const float q1 = bf2f(P[off]);
  const float q2 = bf2f(P[off + 64]);
  P[off]      = f2bf(q1 * cs - q2 * sn);
  P[off + 64] = f2bf(q1 * sn + q2 * cs);
}

// ================= causal flash attention (barrier-free, per-wave, pipelined) =================
// Q,K: [b,s,h*128+d] bf16.  VT: [h*128+d][b*2048+s] bf16 (pre-transposed by gemm).
// K and V^T fragments read DIRECTLY from global (L1/L2-resident; no staging, no
// __syncthreads). K double-buffered in registers (next tile's loads issue under
// softmax). V loads split 4+4 so latency hides under expf chain / first PV MFMAs.
// LPT dispatch: qb descends with blockIdx so 64-tile blocks launch first (tail fix).
// AO may alias Q: each (b,h,row-group) is read and written only by its own wave.
__global__ __launch_bounds__(256, 3) void attn_kernel(
    const u16* __restrict__ Q, const u16* __restrict__ K,
    const u16* __restrict__ VT, u16* __restrict__ AO)
{
  __shared__ float St[4][32 * 17];   // per-wave S^T[key][q], stride 17 (2-way banks)

  const int tid  = threadIdx.x;
  const int wave = tid >> 6;
  const int lane = tid & 63;
  const int quad = lane >> 4;
  const int l15  = lane & 15;
  const int row4 = lane >> 2;   // softmax: q-row owned by this lane group
  const int sub  = lane & 3;    // 4 lanes per row, 8 cols each

  // XCD-aware remap + LPT: xcd = lin&7 keeps each (b,h) group's K/V in one L2;
  // qb = 31 - (idx>>2) makes the 64-tile blocks dispatch FIRST (longest-processing-time
  // order), so the short 1-2-tile blocks backfill the tail instead of creating one.
  const int lin = blockIdx.x;                        // grid 1024, 1-D
  const int xcd = lin & 7;
  const int idx = lin >> 3;                          // 0..127
  const int qb  = 31 - (idx >> 2);                   // 31..0 descending globally
  const int bh  = (xcd << 2) | (idx & 3);            // bijective: 8*4 = 32 bh values
  const int b   = bh >> 4;
  const int h   = bh & 15;

  const long base = (long)b * 2048 * 2048 + (long)h * 128;
  const long vtb  = (long)h * 128 * 4096 + (long)b * 2048;
  const int q0w = qb * 64 + wave * 16;

  const u16* Kp = K + base;
  const u16* Vp = VT + vtb;

  short8 qa[4];
#pragma unroll
  for (int c = 0; c < 4; ++c)
    qa[c] = *(const short8*)&Q[base + (long)(q0w + l15) * 2048 + c * 32 + quad * 8];

  const f32x4 zero = {0.f, 0.f, 0.f, 0.f};
  f32x4 o[8];
#pragma unroll
  for (int c = 0; c < 8; ++c) o[c] = zero;

  float mreg = -1e30f, lreg = 0.f;   // running max / denom for row row4
  float* S = St[wave];
  const float scale = 0.08838834764831845f;  // 1/sqrt(128)
  const int qi = q0w + row4;
  const int psrc = (l15 << 2) | quad;        // src lane for P fragment shuffle

  // waves 0-1 (rows q0w..q0w+31 of the 64-row block) skip the fully-masked last tile.
  // Every processed tile has j0 <= qi for all 16 rows of the wave, so no tile is
  // ever fully masked for any row (the all-masked branch is dead and removed).
  const int njb = qb * 2 + 1 + (wave >> 1);

  // preload K tile 0 into register double-buffer
  short8 kb[8];
#pragma unroll
  for (int c = 0; c < 4; ++c) {
    kb[c]     = *(const short8*)&Kp[(long)(l15) * 2048 + c * 32 + quad * 8];
    kb[c + 4] = *(const short8*)&Kp[(long)(16 + l15) * 2048 + c * 32 + quad * 8];
  }

  for (int jb = 0; jb < njb; ++jb) {
    const int j0 = jb * 32;

    // ---- QK^T from register K fragments ----
    f32x4 s0 = zero, s1 = zero;
#pragma unroll
    for (int c = 0; c < 4; ++c) {
      s0 = __builtin_amdgcn_mfma_f32_16x16x32_bf16(qa[c], kb[c],     s0, 0, 0, 0);
      s1 = __builtin_amdgcn_mfma_f32_16x16x32_bf16(qa[c], kb[c + 4], s1, 0, 0, 0);
    }

    // ---- prefetch next K tile (clamped on last iter; redundant loads harmless) ----
    const int j0n = (jb + 1 < njb ? jb + 1 : jb) * 32;
    short8 kn[8];
#pragma unroll
    for (int c = 0; c < 4; ++c) {
      kn[c]     = *(const short8*)&Kp[(long)(j0n + l15) * 2048 + c * 32 + quad * 8];
      kn[c + 4] = *(const short8*)&Kp[(long)(j0n + 16 + l15) * 2048 + c * 32 + quad * 8];
    }

    // ---- first half of V loads: latency hides under softmax ----
    short8 vb[4];
#pragma unroll
    for (int c = 0; c < 4; ++c)
      vb[c] = *(const short8*)&Vp[(long)(c * 16 + l15) * 4096 + j0 + quad * 8];

    // ---- layout swap via per-wave S^T LDS (write 2-way, read 2-way: free) ----
#pragma unroll
    for (int r = 0; r < 4; ++r) {
      S[l15 * 17 + quad * 4 + r]        = s0[r];
      S[(l15 + 16) * 17 + quad * 4 + r] = s1[r];
    }
    __builtin_amdgcn_wave_barrier();

    // ---- online softmax: row row4, 4 lanes x 8 cols ----
    float sv[8];
    float pmax = -1e30f;
#pragma unroll
    for (int j = 0; j < 8; ++j) {
      const int col = sub * 8 + j;
      float s = S[col * 17 + row4] * scale;
      if (j0 + col > qi) s = -1e30f;
      sv[j] = s;
      pmax = fmaxf(pmax, s);
    }
    __builtin_amdgcn_wave_barrier();
    pmax = fmaxf(pmax, __shfl_xor(pmax, 1, 64));
    pmax = fmaxf(pmax, __shfl_xor(pmax, 2, 64));
    const float mprev = mreg;
    const float mnew  = fmaxf(mprev, pmax);
    const float alpha = __expf(mprev - mnew);   // first tile: exp(-1e30)=0, o==0 anyway
    float psum = 0.f;
#pragma unroll
    for (int j = 0; j < 8; ++j) {
      sv[j] = __expf(sv[j] - mnew);             // masked cols underflow to 0
      psum += sv[j];
    }
    psum += __shfl_xor(psum, 1, 64);
    psum += __shfl_xor(psum, 2, 64);
    lreg = lreg * alpha + psum;
    mreg = mnew;

    // ---- P -> A-fragment layout via 4 shuffles (no LDS round-trip) ----
    short8 pr;
#pragma unroll
    for (int j = 0; j < 8; ++j) pr[j] = (short)f2bf(sv[j]);
    i32x4 pi = *(i32x4*)&pr;
    i32x4 pt;
    pt[0] = __shfl(pi[0], psrc, 64);
    pt[1] = __shfl(pi[1], psrc, 64);
    pt[2] = __shfl(pi[2], psrc, 64);
    pt[3] = __shfl(pi[3], psrc, 64);
    const short8 pa = *(const short8*)&pt;

    // ---- second half of V loads: latency hides under first 4 PV MFMAs ----
    short8 vb2[4];
#pragma unroll
    for (int c = 0; c < 4; ++c)
      vb2[c] = *(const short8*)&Vp[(long)((c + 4) * 16 + l15) * 4096 + j0 + quad * 8];

    // ---- rescale O by alpha of rows quad*4+r (broadcast via shuffle) ----
    float av[4];
#pragma unroll
    for (int r = 0; r < 4; ++r) av[r] = __shfl(alpha, (quad * 4 + r) << 2, 64);
#pragma unroll
    for (int c = 0; c < 8; ++c) {
      o[c][0] *= av[0]; o[c][1] *= av[1]; o[c][2] *= av[2]; o[c][3] *= av[3];
    }

    // ---- PV ----
#pragma unroll
    for (int c = 0; c < 4; ++c)
      o[c] = __builtin_amdgcn_mfma_f32_16x16x32_bf16(pa, vb[c], o[c], 0, 0, 0);
#pragma unroll
    for (int c = 0; c < 4; ++c)
      o[c + 4] = __builtin_amdgcn_mfma_f32_16x16x32_bf16(pa, vb2[c], o[c + 4], 0, 0, 0);

    // ---- rotate K double-buffer ----
#pragma unroll
    for (int i = 0; i < 8; ++i) kb[i] = kn[i];
  }

  // ---- epilogue: normalize and store ----
#pragma unroll
  for (int r = 0; r < 4; ++r) {
    const float lr  = __shfl(lreg, (quad * 4 + r) << 2, 64);
    const float inv = 1.0f / lr;
    const long rowoff = base + (long)(q0w + quad * 4 + r) * 2048;
#pragma unroll
    for (int c = 0; c < 8; ++c)
      AO[rowoff + c * 16 + l15] = f2bf(flushv(o[c][r] * inv, 9999.f));
  }
}

// ================= diagnostic fill =================
__global__ __launch_bounds__(256) void fill_kernel(float* __restrict__ out, long n, float v)
{
  const long t = (long)blockIdx.x * 256 + threadIdx.x;
  if (t < n) out[t] = v;
}

// ================= launch =================
extern "C" void kernel_launch(void* const* d_in, const int* in_sizes, int n_in,
                              void* d_out, int out_size, void* d_ws, size_t ws_size,
                              hipStream_t stream)
{
  // Inputs fp32 (x, Wq, Wk, Wv, Wo); OUTPUT fp32 (reference dtype).
  const float* x  = (const float*)d_in[0];
  const float* Wq = (const float*)d_in[1];
  const float* Wk = (const float*)d_in[2];
  const float* Wv = (const float*)d_in[3];
  const float* Wo = (const float*)d_in[4];
  float* out = (float*)d_out;

  const long QSZ = (long)2 * 2048 * 2048;  // 8388608 elems

  // ws guard (needs 48 MB of bf16 scratch); sentinel 1111 localizes
  if (ws_size < (size_t)3 * QSZ * sizeof(u16)) {
    fill_kernel<<<(int)((QSZ + 255) / 256), 256, 0, stream>>>(out, QSZ, 1111.f);
    return;
  }

  u16* ws = (u16*)d_ws;
  u16* q  = ws;            // bf16 internal
  u16* k  = ws + QSZ;
  u16* v  = ws + 2 * QSZ;  // V^T: [2048 d][4096 tok]
  u16* ao = q;             // attention output in-place over q (partition-safe)

  // sentinels: QKV=7777, attention=9999, outproj=5555, ws=1111
  // Q,K projections: [4096 tok][2048 d]
  gemm_bt<true, true, false><<<dim3(16, 32, 2), 256, 0, stream>>>(
      x, Wq, Wk, Wk, q, k, k, 4096, 2048, 2048, 7777.f);
  // V^T = Wv @ x^T : C[d][tok] = sum_k Wv[d][k] x[tok][k]  -> [2048][4096]
  gemm_bt<true, true, false><<<dim3(32, 16, 1), 256, 0, stream>>>(
      Wv, x, x, x, v, v, v, 2048, 4096, 2048, 7777.f);
  rope_kernel<<<32768, 256, 0, stream>>>(q, k);
  attn_kernel<<<1024, 256, 0, stream>>>(q, k, v, ao);
  gemm_bt<false, true, true><<<dim3(16, 32, 1), 256, 0, stream>>>(
      ao, Wo, Wo, Wo, out, out, out, 4096, 2048, 2048, 5555.f);
}